// Round 1
// baseline (1178.742 us; speedup 1.0000x reference)
//
#include <hip/hip_runtime.h>
#include <cmath>

#define TOK   49
#define WDIM  192
#define NHEADS 6
#define HID   768

typedef __bf16 bf16_t;
typedef bf16_t bf16x8 __attribute__((ext_vector_type(8)));
typedef float  f32x4  __attribute__((ext_vector_type(4)));

#define XLD  200  // 192 + 8 pad (row stride 400B = 4-bank offset per row)
#define QKLD 72   // 64 + 8 pad
#define VTLD 72
#define AOLD 72
#define PLD  40   // 32 + 8 pad
#define HLD  104  // mlp per-wave hidden chunk: 96 + 8 pad (stride 208B)

__device__ __forceinline__ f32x4 mfma16(bf16x8 a, bf16x8 b, f32x4 c) {
    return __builtin_amdgcn_mfma_f32_16x16x32_bf16(a, b, c, 0, 0, 0);
}

__device__ __forceinline__ float gelu_f(float v) {
    // tanh-form gelu as v*sigmoid(2u); max abs err vs erf-form ~3e-4.
    // exp(-u2): +inf for very negative v -> rcp(inf)=0 -> out=0 (correct limit);
    // ->0 for large positive v -> out=v (correct limit). No div sequence.
    float u2 = 1.5957691216057308f * v * __builtin_fmaf(0.044715f, v * v, 1.f);
    float ee = __expf(-u2);
    return v * __builtin_amdgcn_rcpf(1.f + ee);
}

// ---------------- prep: fused weight packing + bias expansion -----------------------
// pack: p = ((nt*KB + kb)*64 + lane)*8 + j <-> W[k = kb*32 + (lane>>4)*8 + j][n = nt*16 + (lane&15)]
__device__ __forceinline__ void pack_one(const float* __restrict__ W, bf16_t* __restrict__ out,
                                         int K, int N, int p) {
    int j    = p & 7;
    int lane = (p >> 3) & 63;
    int kbnt = p >> 9;
    int KB   = K >> 5;
    int kb   = kbnt % KB;
    int nt   = kbnt / KB;
    int n = nt * 16 + (lane & 15);
    int k = kb * 32 + (lane >> 4) * 8 + j;
    out[p] = (bf16_t)W[k * N + n];
}

__global__ void prep_kernel(const float* __restrict__ qkv_w, const float* __restrict__ proj_w,
                            const float* __restrict__ fc1_w, const float* __restrict__ fc2_w,
                            const float* __restrict__ table, const int* __restrict__ rel,
                            bf16_t* __restrict__ qkv_p, bf16_t* __restrict__ proj_p,
                            bf16_t* __restrict__ fc1_p, bf16_t* __restrict__ fc2_p,
                            float* __restrict__ bias6) {
    int b = blockIdx.x, t = threadIdx.x;
    if (b < 432) {
        pack_one(qkv_w, qkv_p, 192, 576, b * 256 + t);
    } else if (b < 576) {
        pack_one(proj_w, proj_p, 192, 192, (b - 432) * 256 + t);
    } else if (b < 1152) {
        pack_one(fc1_w, fc1_p, 192, 768, (b - 576) * 256 + t);
    } else if (b < 1728) {
        pack_one(fc2_w, fc2_p, 768, 192, (b - 1152) * 256 + t);
    } else {
        int p = (b - 1728) * 256 + t;
        if (p < NHEADS * TOK * TOK) {
            int h  = p / (TOK * TOK);
            int mn = p % (TOK * TOK);
            bias6[p] = table[rel[mn] * NHEADS + h];
        }
    }
}

// ---------------- kernel 1: LN1 + window attention + proj + residual ----------------
// one block per window; 4 waves; head-PAIR loop; each wave computes ALL 64 rows
// for 3 of the pair's 12 qkv col-tiles (B fragments loaded once per block).
__global__ void __launch_bounds__(256, 2) attn_kernel(
    const float* __restrict__ x,
    const float* __restrict__ g1, const float* __restrict__ b1,
    const bf16_t* __restrict__ qkv_p, const bf16_t* __restrict__ proj_p,
    const float* __restrict__ proj_b, const float* __restrict__ bias6,
    float* __restrict__ out) {

    __shared__ bf16_t s_xln[64 * XLD];     // 25600 B
    __shared__ bf16_t s_q[64 * QKLD];      //  9216 B (pair: 64 cols)
    __shared__ bf16_t s_k[64 * QKLD];      //  9216 B
    __shared__ bf16_t s_vT[64 * VTLD];     //  9216 B  (vT[d][row])
    __shared__ bf16_t s_ao[64 * AOLD];     //  9216 B  (attn-out, pair cols)
    __shared__ bf16_t s_p[4][16 * PLD];    //  5120 B  (per-wave P buffer)

    const int t    = threadIdx.x;
    const int w    = t >> 6;
    const int lane = t & 63;
    const int l15  = lane & 15;
    const int quad = lane >> 4;
    const int widx = blockIdx.x;
    const float scale = 0.17677669529663687f; // 32^-0.5
    const f32x4 z = {0.f, 0.f, 0.f, 0.f};

    const float* xw = x + (size_t)widx * (TOK * WDIM);

    // ---- LN1: 4 threads per row; rows 49..63 zero-filled ----
    {
        int r = t >> 2, l4 = t & 3;
        if (r < TOK) {
            const float* row = xw + r * WDIM + l4 * 48;
            float s = 0.f, sq = 0.f;
            #pragma unroll
            for (int i = 0; i < 12; i++) {
                float4 f = ((const float4*)row)[i];
                s  += f.x + f.y + f.z + f.w;
                sq += f.x*f.x + f.y*f.y + f.z*f.z + f.w*f.w;
            }
            s  += __shfl_xor(s, 1);  s  += __shfl_xor(s, 2);
            sq += __shfl_xor(sq, 1); sq += __shfl_xor(sq, 2);
            float mean = s * (1.f / WDIM);
            float rstd = rsqrtf(sq * (1.f / WDIM) - mean * mean + 1e-5f);
            #pragma unroll
            for (int i = 0; i < 12; i++) {
                float4 f = ((const float4*)row)[i];
                int c = l4 * 48 + i * 4;
                s_xln[r * XLD + c + 0] = (bf16_t)((f.x - mean) * rstd * g1[c+0] + b1[c+0]);
                s_xln[r * XLD + c + 1] = (bf16_t)((f.y - mean) * rstd * g1[c+1] + b1[c+1]);
                s_xln[r * XLD + c + 2] = (bf16_t)((f.z - mean) * rstd * g1[c+2] + b1[c+2]);
                s_xln[r * XLD + c + 3] = (bf16_t)((f.w - mean) * rstd * g1[c+3] + b1[c+3]);
            }
        } else {
            #pragma unroll
            for (int i = 0; i < 48; i++)
                s_xln[r * XLD + l4 * 48 + i] = (bf16_t)0.f;
        }
    }
    __syncthreads();

    f32x4 pacc[4][3];
    #pragma unroll
    for (int rt = 0; rt < 4; rt++)
        #pragma unroll
        for (int j = 0; j < 3; j++) pacc[rt][j] = z;

    for (int pr = 0; pr < 3; pr++) {
        // ---- phase 1: qkv GEMM for head pair (2pr, 2pr+1) ----
        // pair col-tile np = g*4 + hh*2 + d16 (g: 0=q,1=k,2=v); wave owns np = w*3+j
        f32x4 qa[4][3];
        #pragma unroll
        for (int rt = 0; rt < 4; rt++)
            #pragma unroll
            for (int j = 0; j < 3; j++) qa[rt][j] = z;

        int ntg[3];
        #pragma unroll
        for (int j = 0; j < 3; j++) {
            int np = w * 3 + j;
            int g = np >> 2, hh = (np >> 1) & 1, d16 = np & 1;
            ntg[j] = g * 12 + (2 * pr + hh) * 2 + d16;
        }
        #pragma unroll
        for (int kb = 0; kb < 6; kb++) {
            bf16x8 a[4];
            #pragma unroll
            for (int rt = 0; rt < 4; rt++)
                a[rt] = *(const bf16x8*)&s_xln[(rt * 16 + l15) * XLD + kb * 32 + quad * 8];
            #pragma unroll
            for (int j = 0; j < 3; j++) {
                bf16x8 b = *(const bf16x8*)&qkv_p[(size_t)((ntg[j] * 6 + kb) * 64 + lane) * 8];
                #pragma unroll
                for (int rt = 0; rt < 4; rt++)
                    qa[rt][j] = mfma16(a[rt], b, qa[rt][j]);
            }
        }
        // stage q / k / vT (wave-uniform g per j -> no divergence)
        #pragma unroll
        for (int j = 0; j < 3; j++) {
            int np = w * 3 + j;
            int g = np >> 2;
            int pcol = ((np >> 1) & 1) * 32 + (np & 1) * 16 + l15;
            #pragma unroll
            for (int rt = 0; rt < 4; rt++)
                #pragma unroll
                for (int reg = 0; reg < 4; reg++) {
                    int row = rt * 16 + quad * 4 + reg;
                    bf16_t val = (bf16_t)qa[rt][j][reg];
                    if (g == 0)      s_q[row * QKLD + pcol] = val;
                    else if (g == 1) s_k[row * QKLD + pcol] = val;
                    else             s_vT[pcol * VTLD + row] = val;
                }
        }
        __syncthreads();

        // ---- phase 2: S, softmax, PV per head; wave owns rows w*16..+16 ----
        #pragma unroll
        for (int hh = 0; hh < 2; hh++) {
            int h = 2 * pr + hh;
            bf16x8 aq = *(const bf16x8*)&s_q[(w * 16 + l15) * QKLD + hh * 32 + quad * 8];
            f32x4 sa[4];
            #pragma unroll
            for (int nt = 0; nt < 4; nt++) {
                bf16x8 bk = *(const bf16x8*)&s_k[(nt * 16 + l15) * QKLD + hh * 32 + quad * 8];
                sa[nt] = mfma16(aq, bk, z);
            }
            float p[4][4];
            const float* b6 = bias6 + h * (TOK * TOK);
            #pragma unroll
            for (int nt = 0; nt < 4; nt++) {
                int n  = nt * 16 + l15;
                int nc = (n < TOK) ? n : 0;
                #pragma unroll
                for (int reg = 0; reg < 4; reg++) {
                    int mm = w * 16 + quad * 4 + reg;
                    int mc = (mm < TOK) ? mm : 0;
                    float bias = b6[mc * TOK + nc];
                    p[nt][reg] = (n < TOK) ? (sa[nt][reg] * scale + bias) : -INFINITY;
                }
            }
            #pragma unroll
            for (int reg = 0; reg < 4; reg++) {
                float mx = fmaxf(fmaxf(p[0][reg], p[1][reg]), fmaxf(p[2][reg], p[3][reg]));
                mx = fmaxf(mx, __shfl_xor(mx, 1));
                mx = fmaxf(mx, __shfl_xor(mx, 2));
                mx = fmaxf(mx, __shfl_xor(mx, 4));
                mx = fmaxf(mx, __shfl_xor(mx, 8));
                float sum = 0.f;
                #pragma unroll
                for (int nt = 0; nt < 4; nt++) {
                    float e = __expf(p[nt][reg] - mx);
                    p[nt][reg] = e;
                    sum += e;
                }
                sum += __shfl_xor(sum, 1);
                sum += __shfl_xor(sum, 2);
                sum += __shfl_xor(sum, 4);
                sum += __shfl_xor(sum, 8);
                float rinv = __builtin_amdgcn_rcpf(sum);
                #pragma unroll
                for (int nt = 0; nt < 4; nt++) p[nt][reg] *= rinv;
            }
            // PV: per-wave P round-trip, n-chunked by 32
            bf16_t* pw = s_p[w];
            f32x4 oa[2] = {z, z};
            #pragma unroll
            for (int hf = 0; hf < 2; hf++) {
                #pragma unroll
                for (int i = 0; i < 2; i++) {
                    int nt = hf * 2 + i;
                    #pragma unroll
                    for (int reg = 0; reg < 4; reg++)
                        pw[(quad * 4 + reg) * PLD + i * 16 + l15] = (bf16_t)p[nt][reg];
                }
                bf16x8 ap = *(const bf16x8*)&pw[l15 * PLD + quad * 8];
                #pragma unroll
                for (int dt = 0; dt < 2; dt++) {
                    bf16x8 bv = *(const bf16x8*)&s_vT[(hh * 32 + dt * 16 + l15) * VTLD + hf * 32 + quad * 8];
                    oa[dt] = mfma16(ap, bv, oa[dt]);
                }
            }
            #pragma unroll
            for (int dt = 0; dt < 2; dt++)
                #pragma unroll
                for (int reg = 0; reg < 4; reg++)
                    s_ao[(w * 16 + quad * 4 + reg) * AOLD + hh * 32 + dt * 16 + l15] = (bf16_t)oa[dt][reg];
        }
        __syncthreads();

        // ---- phase 3: proj partial over this pair's 64 attn-out cols ----
        #pragma unroll
        for (int kbp = 0; kbp < 2; kbp++) {
            bf16x8 a[4];
            #pragma unroll
            for (int rt = 0; rt < 4; rt++)
                a[rt] = *(const bf16x8*)&s_ao[(rt * 16 + l15) * AOLD + kbp * 32 + quad * 8];
            #pragma unroll
            for (int j = 0; j < 3; j++) {
                int nt = w * 3 + j;
                bf16x8 b = *(const bf16x8*)&proj_p[(size_t)((nt * 6 + pr * 2 + kbp) * 64 + lane) * 8];
                #pragma unroll
                for (int rt = 0; rt < 4; rt++)
                    pacc[rt][j] = mfma16(a[rt], b, pacc[rt][j]);
            }
        }
        // no barrier needed here: next pair's phase-1 only touches s_xln/s_q/s_k/s_vT,
        // and its post-staging barrier orders everything before s_ao is rewritten.
    }

    // ---- epilogue: out = proj + proj_b + x  (wave writes all 64 rows x its 48 cols)
    float* ow = out + (size_t)widx * (TOK * WDIM);
    #pragma unroll
    for (int rt = 0; rt < 4; rt++)
        #pragma unroll
        for (int j = 0; j < 3; j++) {
            int col = (w * 3 + j) * 16 + l15;
            #pragma unroll
            for (int reg = 0; reg < 4; reg++) {
                int mm = rt * 16 + quad * 4 + reg;
                if (mm < TOK)
                    ow[mm * WDIM + col] = pacc[rt][j][reg] + proj_b[col] + xw[mm * WDIM + col];
            }
        }
}

// ---------------- kernel 2: LN2 + fc1 + gelu + fc2 + residual (in-place on d_out) ---
// BARRIER-FREE main loop: each wave owns 16 ROWS and computes ALL hidden/output cols
// for them. The gelu intermediate lives in a PER-WAVE LDS buffer (16 x 96 chunk), so
// the fc1->fc2 transpose handoff never crosses waves -> no __syncthreads in the loop.
// LDS 25600 + 13312 = 38912 B -> 4 blocks/CU (16 waves) vs previous 51200 B / 3.
// Cost: B-fragments re-read by all 4 waves (4x weight traffic, L2-resident: 590 KB/XCD).
__global__ void __launch_bounds__(256, 4) mlp_kernel(
    float* __restrict__ xio,
    const float* __restrict__ g2, const float* __restrict__ b2,
    const bf16_t* __restrict__ fc1_p, const float* __restrict__ fc1_b,
    const bf16_t* __restrict__ fc2_p, const float* __restrict__ fc2_b) {

    __shared__ bf16_t s_x[64 * XLD];       // 25600 B
    __shared__ bf16_t s_h[4][16 * HLD];    // 13312 B per-wave gelu chunk (16 rows x 96+8)

    const int t    = threadIdx.x;
    const int w    = t >> 6;
    const int lane = t & 63;
    const int l15  = lane & 15;
    const int quad = lane >> 4;
    const f32x4 z = {0.f, 0.f, 0.f, 0.f};
    float* xw = xio + (size_t)blockIdx.x * 64 * WDIM;

    // ---- LN2 (4 threads per row) ----
    {
        int r = t >> 2, l4 = t & 3;
        const float* row = xw + r * WDIM + l4 * 48;
        float s = 0.f, sq = 0.f;
        #pragma unroll
        for (int i = 0; i < 12; i++) {
            float4 f = ((const float4*)row)[i];
            s  += f.x + f.y + f.z + f.w;
            sq += f.x*f.x + f.y*f.y + f.z*f.z + f.w*f.w;
        }
        s  += __shfl_xor(s, 1);  s  += __shfl_xor(s, 2);
        sq += __shfl_xor(sq, 1); sq += __shfl_xor(sq, 2);
        float mean = s * (1.f / WDIM);
        float rstd = rsqrtf(sq * (1.f / WDIM) - mean * mean + 1e-5f);
        #pragma unroll
        for (int i = 0; i < 12; i++) {
            float4 f = ((const float4*)row)[i];
            int c = l4 * 48 + i * 4;
            s_x[r * XLD + c + 0] = (bf16_t)((f.x - mean) * rstd * g2[c+0] + b2[c+0]);
            s_x[r * XLD + c + 1] = (bf16_t)((f.y - mean) * rstd * g2[c+1] + b2[c+1]);
            s_x[r * XLD + c + 2] = (bf16_t)((f.z - mean) * rstd * g2[c+2] + b2[c+2]);
            s_x[r * XLD + c + 3] = (bf16_t)((f.w - mean) * rstd * g2[c+3] + b2[c+3]);
        }
    }
    __syncthreads();   // the ONLY barrier: s_x is read-only from here on

    const int r0 = w * 16;          // wave's 16 token rows
    bf16_t* hw = &s_h[w][0];        // per-wave gelu chunk buffer

    f32x4 fa[12];                   // out accumulator: 12 col-tiles x 4 rows
    #pragma unroll
    for (int j = 0; j < 12; j++) fa[j] = z;

    for (int ch = 0; ch < 8; ch++) {      // 768 = 8 chunks of 96 hidden cols
        // ---- fc1 chunk: own 16 rows x 96 hidden cols (6 col-tiles) ----
        f32x4 ha[6];
        #pragma unroll
        for (int j = 0; j < 6; j++) ha[j] = z;
        #pragma unroll
        for (int kb = 0; kb < 6; kb++) {
            bf16x8 a = *(const bf16x8*)&s_x[(r0 + l15) * XLD + kb * 32 + quad * 8];
            #pragma unroll
            for (int j = 0; j < 6; j++) {
                int ntg = ch * 6 + j;
                bf16x8 b = *(const bf16x8*)&fc1_p[(size_t)((ntg * 6 + kb) * 64 + lane) * 8];
                ha[j] = mfma16(a, b, ha[j]);
            }
        }
        // ---- gelu -> per-wave LDS (rows local 0..15, cols local 0..95) ----
        #pragma unroll
        for (int j = 0; j < 6; j++) {
            float fb = fc1_b[(ch * 6 + j) * 16 + l15];
            #pragma unroll
            for (int reg = 0; reg < 4; reg++)
                hw[(quad * 4 + reg) * HLD + j * 16 + l15] = (bf16_t)gelu_f(ha[j][reg] + fb);
        }
        // no barrier: same-wave RAW on LDS is ordered by lgkmcnt
        // ---- fc2 partial over this chunk's 96 k values ----
        #pragma unroll
        for (int kc = 0; kc < 3; kc++) {
            bf16x8 a2 = *(const bf16x8*)&hw[l15 * HLD + kc * 32 + quad * 8];
            int kbg = ch * 3 + kc;
            #pragma unroll
            for (int j = 0; j < 12; j++) {
                bf16x8 b = *(const bf16x8*)&fc2_p[(size_t)((j * 24 + kbg) * 64 + lane) * 8];
                fa[j] = mfma16(a2, b, fa[j]);
            }
        }
    }

    // ---- epilogue: out = fc2 + fc2_b + x' (in place; wave's own 16 rows) ----
    #pragma unroll
    for (int j = 0; j < 12; j++) {
        int col = j * 16 + l15;
        float fb = fc2_b[col];
        #pragma unroll
        for (int reg = 0; reg < 4; reg++) {
            int r = r0 + quad * 4 + reg;
            float* ptr = xw + r * WDIM + col;
            *ptr = fa[j][reg] + fb + *ptr;
        }
    }
}

// ---------------- launch ------------------------------------------------------------
extern "C" void kernel_launch(void* const* d_in, const int* in_sizes, int n_in,
                              void* d_out, int out_size, void* d_ws, size_t ws_size,
                              hipStream_t stream) {
    const float* x      = (const float*)d_in[0];
    const float* ln1_g  = (const float*)d_in[1];
    const float* ln1_b  = (const float*)d_in[2];
    const float* qkv_w  = (const float*)d_in[3];
    const float* proj_w = (const float*)d_in[4];
    const float* proj_b = (const float*)d_in[5];
    const float* bias_t = (const float*)d_in[6];
    const float* ln2_g  = (const float*)d_in[7];
    const float* ln2_b  = (const float*)d_in[8];
    const float* fc1_w  = (const float*)d_in[9];
    const float* fc1_b  = (const float*)d_in[10];
    const float* fc2_w  = (const float*)d_in[11];
    const float* fc2_b  = (const float*)d_in[12];
    const int*   rel    = (const int*)d_in[13];
    float* out = (float*)d_out;

    char* ws = (char*)d_ws;
    bf16_t* qkv_p  = (bf16_t*)(ws);               // 110592 bf16 = 221184 B
    bf16_t* proj_p = (bf16_t*)(ws + 221184);      //  36864 bf16 =  73728 B
    bf16_t* fc1_p  = (bf16_t*)(ws + 294912);      // 147456 bf16 = 294912 B
    bf16_t* fc2_p  = (bf16_t*)(ws + 589824);      // 147456 bf16 = 294912 B
    float*  bias6  = (float*) (ws + 884736);      //  14406 f32  =  57624 B

    // single fused prep launch (was 5 small launches)
    prep_kernel<<<1785, 256, 0, stream>>>(qkv_w, proj_w, fc1_w, fc2_w, bias_t, rel,
                                          qkv_p, proj_p, fc1_p, fc2_p, bias6);

    attn_kernel<<<4096, 256, 0, stream>>>(x, ln1_g, ln1_b, qkv_p, proj_p, proj_b, bias6, out);
    mlp_kernel<<<3136, 256, 0, stream>>>(out, ln2_g, ln2_b, fc1_p, fc1_b, fc2_p, fc2_b);
}

// Round 2
// 779.285 us; speedup vs baseline: 1.5126x; 1.5126x over previous
//
#include <hip/hip_runtime.h>
#include <cmath>

#define TOK   49
#define WDIM  192
#define NHEADS 6
#define HID   768

typedef __bf16 bf16_t;
typedef bf16_t bf16x8 __attribute__((ext_vector_type(8)));
typedef bf16_t bf16x4 __attribute__((ext_vector_type(4)));
typedef float  f32x4  __attribute__((ext_vector_type(4)));

#define XLD  200  // 192 + 8 pad
#define QKLD 72   // 64 + 8 pad
#define VTLD 72
#define AOLD 72
#define PLD  72   // full pair width 64 + 8 pad
#define HLD2 200  // mlp hidden chunk 192 + 8 pad

#define LOG2E 1.4426950408889634f
// scale * log2e : (32^-0.5) * log2e
#define SCL_L2E 0.25503489f

__device__ __forceinline__ f32x4 mfma16(bf16x8 a, bf16x8 b, f32x4 c) {
    return __builtin_amdgcn_mfma_f32_16x16x32_bf16(a, b, c, 0, 0, 0);
}

__device__ __forceinline__ float exp2_fast(float x) {
#if __has_builtin(__builtin_amdgcn_exp2f)
    return __builtin_amdgcn_exp2f(x);
#else
    return __expf(x * 0.6931471805599453f);
#endif
}

__device__ __forceinline__ bf16x4 pack4(f32x4 v) {
    bf16x4 r;
    r[0] = (bf16_t)v[0]; r[1] = (bf16_t)v[1];
    r[2] = (bf16_t)v[2]; r[3] = (bf16_t)v[3];
    return r;
}

__device__ __forceinline__ float gelu_f(float v) {
    // v * sigmoid(2u), exp2 form (log2e folded); correct limits at both ends.
    float u2n = -2.3022084f * v * __builtin_fmaf(0.044715f, v * v, 1.f);
    float ee = exp2_fast(u2n);
    return v * __builtin_amdgcn_rcpf(1.f + ee);
}

// ---------------- prep: fused weight packing + bias expansion -----------------------
// pack: p = ((nt*KB + kb)*64 + lane)*8 + j <-> W[k = kb*32 + (lane>>4)*8 + j][n = nt*16 + (lane&15)]
__device__ __forceinline__ void pack_one(const float* __restrict__ W, bf16_t* __restrict__ out,
                                         int K, int N, int p) {
    int j    = p & 7;
    int lane = (p >> 3) & 63;
    int kbnt = p >> 9;
    int KB   = K >> 5;
    int kb   = kbnt % KB;
    int nt   = kbnt / KB;
    int n = nt * 16 + (lane & 15);
    int k = kb * 32 + (lane >> 4) * 8 + j;
    out[p] = (bf16_t)W[k * N + n];
}

__global__ void prep_kernel(const float* __restrict__ qkv_w, const float* __restrict__ proj_w,
                            const float* __restrict__ fc1_w, const float* __restrict__ fc2_w,
                            const float* __restrict__ table, const int* __restrict__ rel,
                            bf16_t* __restrict__ qkv_p, bf16_t* __restrict__ proj_p,
                            bf16_t* __restrict__ fc1_p, bf16_t* __restrict__ fc2_p,
                            float* __restrict__ bias6) {
    int b = blockIdx.x, t = threadIdx.x;
    if (b < 432) {
        pack_one(qkv_w, qkv_p, 192, 576, b * 256 + t);
    } else if (b < 576) {
        pack_one(proj_w, proj_p, 192, 192, (b - 432) * 256 + t);
    } else if (b < 1152) {
        pack_one(fc1_w, fc1_p, 192, 768, (b - 576) * 256 + t);
    } else if (b < 1728) {
        pack_one(fc2_w, fc2_p, 768, 192, (b - 1152) * 256 + t);
    } else {
        // bias: [h][m(49)][n padded to 64]; pre-scaled by log2e; pad = -80 (exp2 -> 0)
        int p = (b - 1728) * 256 + t;
        if (p < NHEADS * TOK * 64) {
            int n   = p & 63;
            int rem = p >> 6;          // h*49 + m
            int m   = rem % TOK;
            int h   = rem / TOK;
            bias6[p] = (n < TOK) ? table[rel[m * TOK + n] * NHEADS + h] * LOG2E : -80.f;
        }
    }
}

// ---------------- kernel 1: LN1 + window attention + proj + residual ----------------
// one block per window; 4 waves; head-PAIR loop.
// Wave w owns qkv pair-col-tiles np = w + 4j (j=0:q, j=1:k, j=2:v), pair col base w*16.
// q/k use SWAPPED mfma (lane holds 4 consecutive cols of one row -> b64 staging);
// v uses normal orientation (lane holds 4 consecutive rows of one col -> b64 vT staging).
__global__ void __launch_bounds__(256, 2) attn_kernel(
    const float* __restrict__ x,
    const float* __restrict__ g1, const float* __restrict__ b1,
    const bf16_t* __restrict__ qkv_p, const bf16_t* __restrict__ proj_p,
    const float* __restrict__ proj_b, const float* __restrict__ bias6,
    float* __restrict__ out) {

    __shared__ bf16_t s_xln[64 * XLD];     // 25600 B
    __shared__ bf16_t s_q[64 * QKLD];      //  9216 B
    __shared__ bf16_t s_k[64 * QKLD];      //  9216 B
    __shared__ bf16_t s_vT[64 * VTLD];     //  9216 B  (vT[d][row])
    __shared__ bf16_t s_ao[64 * AOLD];     //  9216 B
    __shared__ bf16_t s_p[4][16 * PLD];    //  9216 B  (per-wave P rows, full 64 n)

    const int t    = threadIdx.x;
    const int w    = t >> 6;
    const int lane = t & 63;
    const int l15  = lane & 15;
    const int quad = lane >> 4;
    const int widx = blockIdx.x;
    const f32x4 z = {0.f, 0.f, 0.f, 0.f};

    const float* xw = x + (size_t)widx * (TOK * WDIM);

    // ---- LN1: 4 threads per row; rows 49..63 zero-filled ----
    {
        int r = t >> 2, l4 = t & 3;
        if (r < TOK) {
            const float* row = xw + r * WDIM + l4 * 48;
            float s = 0.f, sq = 0.f;
            #pragma unroll
            for (int i = 0; i < 12; i++) {
                float4 f = ((const float4*)row)[i];
                s  += f.x + f.y + f.z + f.w;
                sq += f.x*f.x + f.y*f.y + f.z*f.z + f.w*f.w;
            }
            s  += __shfl_xor(s, 1);  s  += __shfl_xor(s, 2);
            sq += __shfl_xor(sq, 1); sq += __shfl_xor(sq, 2);
            float mean = s * (1.f / WDIM);
            float rstd = rsqrtf(sq * (1.f / WDIM) - mean * mean + 1e-5f);
            #pragma unroll
            for (int i = 0; i < 12; i++) {
                float4 f = ((const float4*)row)[i];
                int c = l4 * 48 + i * 4;
                f32x4 v;
                v[0] = (f.x - mean) * rstd * g1[c+0] + b1[c+0];
                v[1] = (f.y - mean) * rstd * g1[c+1] + b1[c+1];
                v[2] = (f.z - mean) * rstd * g1[c+2] + b1[c+2];
                v[3] = (f.w - mean) * rstd * g1[c+3] + b1[c+3];
                *(bf16x4*)&s_xln[r * XLD + c] = pack4(v);
            }
        } else {
            bf16x8 zz = {};
            #pragma unroll
            for (int i = 0; i < 6; i++)
                *(bf16x8*)&s_xln[r * XLD + l4 * 48 + i * 8] = zz;
        }
    }
    __syncthreads();

    f32x4 pacc[4][3];
    #pragma unroll
    for (int rt = 0; rt < 4; rt++)
        #pragma unroll
        for (int j = 0; j < 3; j++) pacc[rt][j] = z;

    for (int pr = 0; pr < 3; pr++) {
        // ---- phase 1: qkv GEMM for head pair (2pr, 2pr+1) ----
        f32x4 qa[4][3];
        #pragma unroll
        for (int rt = 0; rt < 4; rt++)
            #pragma unroll
            for (int j = 0; j < 3; j++) qa[rt][j] = z;

        int ntg[3];
        #pragma unroll
        for (int j = 0; j < 3; j++)   // np = w + 4j -> g=j, hh=w>>1, d16=w&1
            ntg[j] = j * 12 + (2 * pr + (w >> 1)) * 2 + (w & 1);

        #pragma unroll
        for (int kb = 0; kb < 6; kb++) {
            bf16x8 a[4];
            #pragma unroll
            for (int rt = 0; rt < 4; rt++)
                a[rt] = *(const bf16x8*)&s_xln[(rt * 16 + l15) * XLD + kb * 32 + quad * 8];
            #pragma unroll
            for (int j = 0; j < 3; j++) {
                bf16x8 b = *(const bf16x8*)&qkv_p[(size_t)((ntg[j] * 6 + kb) * 64 + lane) * 8];
                if (j < 2) {   // q,k: swapped -> lane holds [row = rt*16+l15][col quad*4+reg]
                    #pragma unroll
                    for (int rt = 0; rt < 4; rt++)
                        qa[rt][j] = mfma16(b, a[rt], qa[rt][j]);
                } else {       // v: normal -> lane holds [row rt*16+quad*4+reg][col l15]
                    #pragma unroll
                    for (int rt = 0; rt < 4; rt++)
                        qa[rt][j] = mfma16(a[rt], b, qa[rt][j]);
                }
            }
        }
        // stage: all b64 writes
        #pragma unroll
        for (int rt = 0; rt < 4; rt++) {
            *(bf16x4*)&s_q [(rt * 16 + l15) * QKLD + w * 16 + quad * 4] = pack4(qa[rt][0]);
            *(bf16x4*)&s_k [(rt * 16 + l15) * QKLD + w * 16 + quad * 4] = pack4(qa[rt][1]);
            *(bf16x4*)&s_vT[(w * 16 + l15) * VTLD + rt * 16 + quad * 4] = pack4(qa[rt][2]);
        }
        __syncthreads();

        // ---- phase 2: S^T, softmax (row-local), PV^T; wave owns rows m = w*16+l15 ----
        const int mrow = w * 16 + l15;
        const int mc   = (mrow < TOK) ? mrow : 0;
        #pragma unroll
        for (int hh = 0; hh < 2; hh++) {
            int h = 2 * pr + hh;
            bf16x8 aq = *(const bf16x8*)&s_q[mrow * QKLD + hh * 32 + quad * 8];
            f32x4 sa[4];
            #pragma unroll
            for (int nt = 0; nt < 4; nt++) {
                bf16x8 bk = *(const bf16x8*)&s_k[(nt * 16 + l15) * QKLD + hh * 32 + quad * 8];
                sa[nt] = mfma16(bk, aq, z);   // swapped: lane holds S[m=mrow][n = nt*16+quad*4+reg]
            }
            // bias (+pad=-80 handles n>=49), exp2; no max-subtract (logits |.|<~1)
            const float* bp = bias6 + ((size_t)h * TOK + mc) * 64;
            f32x4 p[4];
            float sum = 0.f;
            #pragma unroll
            for (int nt = 0; nt < 4; nt++) {
                float4 bb = *(const float4*)&bp[nt * 16 + quad * 4];
                p[nt][0] = exp2_fast(__builtin_fmaf(sa[nt][0], SCL_L2E, bb.x));
                p[nt][1] = exp2_fast(__builtin_fmaf(sa[nt][1], SCL_L2E, bb.y));
                p[nt][2] = exp2_fast(__builtin_fmaf(sa[nt][2], SCL_L2E, bb.z));
                p[nt][3] = exp2_fast(__builtin_fmaf(sa[nt][3], SCL_L2E, bb.w));
                sum += (p[nt][0] + p[nt][1]) + (p[nt][2] + p[nt][3]);
            }
            sum += __shfl_xor(sum, 16);
            sum += __shfl_xor(sum, 32);
            float rinv = __builtin_amdgcn_rcpf(sum);

            // P -> per-wave LDS (unnormalized, b64 writes), then PV swapped
            bf16_t* pw = s_p[w];
            #pragma unroll
            for (int nt = 0; nt < 4; nt++)
                *(bf16x4*)&pw[l15 * PLD + nt * 16 + quad * 4] = pack4(p[nt]);

            f32x4 oa[2] = {z, z};
            #pragma unroll
            for (int hf = 0; hf < 2; hf++) {
                bf16x8 ap = *(const bf16x8*)&pw[l15 * PLD + hf * 32 + quad * 8];
                #pragma unroll
                for (int dt = 0; dt < 2; dt++) {
                    bf16x8 bv = *(const bf16x8*)&s_vT[(hh * 32 + dt * 16 + l15) * VTLD + hf * 32 + quad * 8];
                    oa[dt] = mfma16(bv, ap, oa[dt]);  // swapped: lane holds AO[m=mrow][d consec]
                }
            }
            #pragma unroll
            for (int dt = 0; dt < 2; dt++) {
                f32x4 o = oa[dt];
                o[0] *= rinv; o[1] *= rinv; o[2] *= rinv; o[3] *= rinv;
                *(bf16x4*)&s_ao[mrow * AOLD + hh * 32 + dt * 16 + quad * 4] = pack4(o);
            }
        }
        __syncthreads();

        // ---- phase 3: proj partial (swapped) over this pair's 64 attn-out cols ----
        #pragma unroll
        for (int kbp = 0; kbp < 2; kbp++) {
            bf16x8 a[4];
            #pragma unroll
            for (int rt = 0; rt < 4; rt++)
                a[rt] = *(const bf16x8*)&s_ao[(rt * 16 + l15) * AOLD + kbp * 32 + quad * 8];
            #pragma unroll
            for (int j = 0; j < 3; j++) {
                int nt = w * 3 + j;
                bf16x8 b = *(const bf16x8*)&proj_p[(size_t)((nt * 6 + pr * 2 + kbp) * 64 + lane) * 8];
                #pragma unroll
                for (int rt = 0; rt < 4; rt++)
                    pacc[rt][j] = mfma16(b, a[rt], pacc[rt][j]);  // swapped
            }
        }
        // no barrier: next staging only writes s_q/s_k/s_vT, ordered by its own barrier
    }

    // ---- epilogue: float4 out = proj + proj_b + x ----
    float* ow = out + (size_t)widx * (TOK * WDIM);
    #pragma unroll
    for (int rt = 0; rt < 4; rt++) {
        int row = rt * 16 + l15;
        if (row < TOK) {
            #pragma unroll
            for (int j = 0; j < 3; j++) {
                int cb = (w * 3 + j) * 16 + quad * 4;
                float4 pb = *(const float4*)&proj_b[cb];
                float4 r  = *(const float4*)&xw[row * WDIM + cb];
                float4 o;
                o.x = pacc[rt][j][0] + pb.x + r.x;
                o.y = pacc[rt][j][1] + pb.y + r.y;
                o.z = pacc[rt][j][2] + pb.z + r.z;
                o.w = pacc[rt][j][3] + pb.w + r.w;
                *(float4*)&ow[row * WDIM + cb] = o;
            }
        }
    }
}

// ---------------- kernel 2: LN2 + fc1 + gelu + fc2 + residual (in-place) ------------
// Round-0 column-ownership structure (4 MFMAs per B-load) + swapped mfma everywhere:
// b64 LDS staging, float4 epilogue.
__global__ void __launch_bounds__(256, 2) mlp_kernel(
    float* __restrict__ xio,
    const float* __restrict__ g2, const float* __restrict__ b2,
    const bf16_t* __restrict__ fc1_p, const float* __restrict__ fc1_b,
    const bf16_t* __restrict__ fc2_p, const float* __restrict__ fc2_b) {

    __shared__ bf16_t s_x[64 * XLD];       // 25600 B
    __shared__ bf16_t s_h[64 * HLD2];      // 25600 B -> 51.2 KB total, 3 blocks/CU

    const int t    = threadIdx.x;
    const int w    = t >> 6;
    const int lane = t & 63;
    const int l15  = lane & 15;
    const int quad = lane >> 4;
    const f32x4 z = {0.f, 0.f, 0.f, 0.f};
    float* xw = xio + (size_t)blockIdx.x * 64 * WDIM;

    // ---- LN2 ----
    {
        int r = t >> 2, l4 = t & 3;
        const float* row = xw + r * WDIM + l4 * 48;
        float s = 0.f, sq = 0.f;
        #pragma unroll
        for (int i = 0; i < 12; i++) {
            float4 f = ((const float4*)row)[i];
            s  += f.x + f.y + f.z + f.w;
            sq += f.x*f.x + f.y*f.y + f.z*f.z + f.w*f.w;
        }
        s  += __shfl_xor(s, 1);  s  += __shfl_xor(s, 2);
        sq += __shfl_xor(sq, 1); sq += __shfl_xor(sq, 2);
        float mean = s * (1.f / WDIM);
        float rstd = rsqrtf(sq * (1.f / WDIM) - mean * mean + 1e-5f);
        #pragma unroll
        for (int i = 0; i < 12; i++) {
            float4 f = ((const float4*)row)[i];
            int c = l4 * 48 + i * 4;
            f32x4 v;
            v[0] = (f.x - mean) * rstd * g2[c+0] + b2[c+0];
            v[1] = (f.y - mean) * rstd * g2[c+1] + b2[c+1];
            v[2] = (f.z - mean) * rstd * g2[c+2] + b2[c+2];
            v[3] = (f.w - mean) * rstd * g2[c+3] + b2[c+3];
            *(bf16x4*)&s_x[r * XLD + c] = pack4(v);
        }
    }
    __syncthreads();

    f32x4 fa[4][3];
    #pragma unroll
    for (int rt = 0; rt < 4; rt++)
        #pragma unroll
        for (int j = 0; j < 3; j++) fa[rt][j] = z;

    for (int ch = 0; ch < 4; ch++) {       // 768 = 4 chunks of 192 hidden cols
        // ---- fc1 chunk (swapped): wave owns 3 of 12 col-tiles, all 64 rows ----
        f32x4 ha[4][3];
        #pragma unroll
        for (int rt = 0; rt < 4; rt++)
            #pragma unroll
            for (int j = 0; j < 3; j++) ha[rt][j] = z;
        #pragma unroll
        for (int kb = 0; kb < 6; kb++) {
            bf16x8 a[4];
            #pragma unroll
            for (int rt = 0; rt < 4; rt++)
                a[rt] = *(const bf16x8*)&s_x[(rt * 16 + l15) * XLD + kb * 32 + quad * 8];
            #pragma unroll
            for (int j = 0; j < 3; j++) {
                int ntg = ch * 12 + w * 3 + j;
                bf16x8 b = *(const bf16x8*)&fc1_p[(size_t)((ntg * 6 + kb) * 64 + lane) * 8];
                #pragma unroll
                for (int rt = 0; rt < 4; rt++)
                    ha[rt][j] = mfma16(b, a[rt], ha[rt][j]);   // lane: H[rt*16+l15][tile+quad*4+reg]
            }
        }
        // gelu -> s_h (b64 writes)
        #pragma unroll
        for (int j = 0; j < 3; j++) {
            int colg = (ch * 12 + w * 3 + j) * 16 + quad * 4;
            float4 fb = *(const float4*)&fc1_b[colg];
            int colc = (w * 3 + j) * 16 + quad * 4;
            #pragma unroll
            for (int rt = 0; rt < 4; rt++) {
                f32x4 hv;
                hv[0] = gelu_f(ha[rt][j][0] + fb.x);
                hv[1] = gelu_f(ha[rt][j][1] + fb.y);
                hv[2] = gelu_f(ha[rt][j][2] + fb.z);
                hv[3] = gelu_f(ha[rt][j][3] + fb.w);
                *(bf16x4*)&s_h[(rt * 16 + l15) * HLD2 + colc] = pack4(hv);
            }
        }
        __syncthreads();
        // ---- fc2 partial (swapped) over this chunk's 192 k values ----
        #pragma unroll
        for (int kc = 0; kc < 6; kc++) {
            bf16x8 a2[4];
            #pragma unroll
            for (int rt = 0; rt < 4; rt++)
                a2[rt] = *(const bf16x8*)&s_h[(rt * 16 + l15) * HLD2 + kc * 32 + quad * 8];
            int kbg = ch * 6 + kc;
            #pragma unroll
            for (int j = 0; j < 3; j++) {
                int nt = w * 3 + j;
                bf16x8 b = *(const bf16x8*)&fc2_p[(size_t)((nt * 24 + kbg) * 64 + lane) * 8];
                #pragma unroll
                for (int rt = 0; rt < 4; rt++)
                    fa[rt][j] = mfma16(b, a2[rt], fa[rt][j]);  // lane: OUT[rt*16+l15][tile+quad*4+reg]
            }
        }
        __syncthreads();   // before next chunk overwrites s_h
    }

    // ---- epilogue: float4 out = fc2 + fc2_b + x' (in place) ----
    #pragma unroll
    for (int rt = 0; rt < 4; rt++) {
        int row = rt * 16 + l15;
        #pragma unroll
        for (int j = 0; j < 3; j++) {
            int cb = (w * 3 + j) * 16 + quad * 4;
            float4 fb = *(const float4*)&fc2_b[cb];
            float* ptr = xw + row * WDIM + cb;
            float4 r = *(const float4*)ptr;
            float4 o;
            o.x = fa[rt][j][0] + fb.x + r.x;
            o.y = fa[rt][j][1] + fb.y + r.y;
            o.z = fa[rt][j][2] + fb.z + r.z;
            o.w = fa[rt][j][3] + fb.w + r.w;
            *(float4*)ptr = o;
        }
    }
}

// ---------------- launch ------------------------------------------------------------
extern "C" void kernel_launch(void* const* d_in, const int* in_sizes, int n_in,
                              void* d_out, int out_size, void* d_ws, size_t ws_size,
                              hipStream_t stream) {
    const float* x      = (const float*)d_in[0];
    const float* ln1_g  = (const float*)d_in[1];
    const float* ln1_b  = (const float*)d_in[2];
    const float* qkv_w  = (const float*)d_in[3];
    const float* proj_w = (const float*)d_in[4];
    const float* proj_b = (const float*)d_in[5];
    const float* bias_t = (const float*)d_in[6];
    const float* ln2_g  = (const float*)d_in[7];
    const float* ln2_b  = (const float*)d_in[8];
    const float* fc1_w  = (const float*)d_in[9];
    const float* fc1_b  = (const float*)d_in[10];
    const float* fc2_w  = (const float*)d_in[11];
    const float* fc2_b  = (const float*)d_in[12];
    const int*   rel    = (const int*)d_in[13];
    float* out = (float*)d_out;

    char* ws = (char*)d_ws;
    bf16_t* qkv_p  = (bf16_t*)(ws);               // 110592 bf16 = 221184 B
    bf16_t* proj_p = (bf16_t*)(ws + 221184);      //  36864 bf16 =  73728 B
    bf16_t* fc1_p  = (bf16_t*)(ws + 294912);      // 147456 bf16 = 294912 B
    bf16_t* fc2_p  = (bf16_t*)(ws + 589824);      // 147456 bf16 = 294912 B
    float*  bias6  = (float*) (ws + 884736);      // 6*49*64 f32 = 75264 B (total 960000)

    // fused prep: 1728 pack blocks + 74 bias blocks
    prep_kernel<<<1802, 256, 0, stream>>>(qkv_w, proj_w, fc1_w, fc2_w, bias_t, rel,
                                          qkv_p, proj_p, fc1_p, fc2_p, bias6);

    attn_kernel<<<4096, 256, 0, stream>>>(x, ln1_g, ln1_b, qkv_p, proj_p, proj_b, bias6, out);
    mlp_kernel<<<3136, 256, 0, stream>>>(out, ln2_g, ln2_b, fc1_p, fc1_b, fc2_p, fc2_b);
}